// Round 8
// baseline (202.475 us; speedup 1.0000x reference)
//
#include <hip/hip_runtime.h>
#include <math.h>

// Softmax over last dim. x: (2,16,2048,2048) fp32 -> out fp32, same shape.
// 65536 rows of 2048 floats. Persistent-style grid: 2048 blocks (8/CU,
// all co-resident at 8 waves/SIMD), each wave loops over 8 contiguous
// rows. NT load + NT store (both-NT won the R1/R3/R5/R6 2x2).
// VGPR <= 64 via __launch_bounds__(256,8) (R7: +3.8%). Loop lets next
// row's loads issue behind previous row's stores - no block churn.

#define ROW_LEN       2048
#define CHUNKS        8      // per lane per row: (2048/4) / 64
#define ROWS_PER_WAVE 8

typedef float f32x4 __attribute__((ext_vector_type(4)));

__global__ __launch_bounds__(256, 8) void softmax_row_kernel(
        const float* __restrict__ x, float* __restrict__ out, int nrows) {
    const int wave = threadIdx.x >> 6;   // 0..3
    const int lane = threadIdx.x & 63;
    const long long gwid = (long long)blockIdx.x * 4 + wave;
    const long long row0 = gwid * ROWS_PER_WAVE;

    for (int r = 0; r < ROWS_PER_WAVE; ++r) {
        const long long row = row0 + r;
        if (row >= nrows) return;

        const f32x4* __restrict__ xr =
            reinterpret_cast<const f32x4*>(x + (size_t)row * ROW_LEN);
        f32x4* __restrict__ outr =
            reinterpret_cast<f32x4*>(out + (size_t)row * ROW_LEN);

        f32x4 v[CHUNKS];
#pragma unroll
        for (int k = 0; k < CHUNKS; ++k)
            v[k] = __builtin_nontemporal_load(&xr[lane + 64 * k]);

        // ---- row max ----
        float m = -INFINITY;
#pragma unroll
        for (int k = 0; k < CHUNKS; ++k)
            m = fmaxf(m, fmaxf(fmaxf(v[k].x, v[k].y), fmaxf(v[k].z, v[k].w)));
#pragma unroll
        for (int off = 32; off >= 1; off >>= 1)
            m = fmaxf(m, __shfl_xor(m, off, 64));

        // ---- exp + row sum ----
        float s = 0.f;
#pragma unroll
        for (int k = 0; k < CHUNKS; ++k) {
            v[k].x = __expf(v[k].x - m);
            v[k].y = __expf(v[k].y - m);
            v[k].z = __expf(v[k].z - m);
            v[k].w = __expf(v[k].w - m);
            s += (v[k].x + v[k].y) + (v[k].z + v[k].w);
        }
#pragma unroll
        for (int off = 32; off >= 1; off >>= 1)
            s += __shfl_xor(s, off, 64);

        const float inv = 1.0f / s;

        // ---- scale + store (non-temporal) ----
#pragma unroll
        for (int k = 0; k < CHUNKS; ++k) {
            f32x4 t = v[k] * inv;
            __builtin_nontemporal_store(t, &outr[lane + 64 * k]);
        }
    }
}

extern "C" void kernel_launch(void* const* d_in, const int* in_sizes, int n_in,
                              void* d_out, int out_size, void* d_ws, size_t ws_size,
                              hipStream_t stream) {
    const float* x = (const float*)d_in[0];
    float* out = (float*)d_out;
    const int nrows = in_sizes[0] / ROW_LEN;                 // 65536
    const long long waves = (nrows + ROWS_PER_WAVE - 1) / ROWS_PER_WAVE;
    const int blocks = (int)((waves + 3) / 4);               // 2048
    softmax_row_kernel<<<blocks, 256, 0, stream>>>(x, out, nrows);
}

// Round 9
// 181.056 us; speedup vs baseline: 1.1183x; 1.1183x over previous
//
#include <hip/hip_runtime.h>
#include <math.h>

// Softmax over last dim. x: (2,16,2048,2048) fp32 -> out fp32, same shape.
// 65536 rows of 2048 floats. One wave (64 lanes) per row; 32 floats/lane
// in registers. FINAL CONFIG (= R7, best at 182.8 us = 5.87 TB/s):
//  - NT load + NT store: both-NT is the only winning cell of the R1/R3/
//    R5/R6 cache-op 2x2 (+5%). Single-sided NT is neutral/negative.
//  - __launch_bounds__(256,8): caps VGPR at 64 -> 8 waves/SIMD (m69
//    occupancy step), doubling per-CU in-flight bytes (+3.8%, R7).
//  - 16384 small blocks, one row per wave: dynamic block scheduling.
//    Persistent 2048-block static partition regressed 11% (R8); intra-
//    wave double-buffer pipelining was neutral (R4). Do not re-try.

#define ROW_LEN   2048
#define CHUNKS     8               // per lane: (2048/4) / 64

typedef float f32x4 __attribute__((ext_vector_type(4)));

__global__ __launch_bounds__(256, 8) void softmax_row_kernel(
        const float* __restrict__ x, float* __restrict__ out, int nrows) {
    const int wave = threadIdx.x >> 6;   // 0..3
    const int lane = threadIdx.x & 63;
    const long long row = (long long)blockIdx.x * 4 + wave;
    if (row >= nrows) return;

    const f32x4* __restrict__ xr =
        reinterpret_cast<const f32x4*>(x + (size_t)row * ROW_LEN);
    f32x4* __restrict__ outr =
        reinterpret_cast<f32x4*>(out + (size_t)row * ROW_LEN);

    f32x4 v[CHUNKS];
#pragma unroll
    for (int k = 0; k < CHUNKS; ++k)
        v[k] = __builtin_nontemporal_load(&xr[lane + 64 * k]);

    // ---- row max ----
    float m = -INFINITY;
#pragma unroll
    for (int k = 0; k < CHUNKS; ++k) {
        m = fmaxf(m, fmaxf(fmaxf(v[k].x, v[k].y), fmaxf(v[k].z, v[k].w)));
    }
#pragma unroll
    for (int off = 32; off >= 1; off >>= 1)
        m = fmaxf(m, __shfl_xor(m, off, 64));

    // ---- exp + row sum ----
    float s = 0.f;
#pragma unroll
    for (int k = 0; k < CHUNKS; ++k) {
        v[k].x = __expf(v[k].x - m);
        v[k].y = __expf(v[k].y - m);
        v[k].z = __expf(v[k].z - m);
        v[k].w = __expf(v[k].w - m);
        s += (v[k].x + v[k].y) + (v[k].z + v[k].w);
    }
#pragma unroll
    for (int off = 32; off >= 1; off >>= 1)
        s += __shfl_xor(s, off, 64);

    const float inv = 1.0f / s;

    // ---- scale + store (non-temporal) ----
#pragma unroll
    for (int k = 0; k < CHUNKS; ++k) {
        v[k] *= inv;
        __builtin_nontemporal_store(v[k], &outr[lane + 64 * k]);
    }
}

extern "C" void kernel_launch(void* const* d_in, const int* in_sizes, int n_in,
                              void* d_out, int out_size, void* d_ws, size_t ws_size,
                              hipStream_t stream) {
    const float* x = (const float*)d_in[0];
    float* out = (float*)d_out;
    const int nrows = in_sizes[0] / ROW_LEN;          // 65536
    const int blocks = (nrows + 3) / 4;               // 4 rows per block
    softmax_row_kernel<<<blocks, 256, 0, stream>>>(x, out, nrows);
}